// Round 1
// baseline (62.448 us; speedup 1.0000x reference)
//
#include <hip/hip_runtime.h>
#include <math.h>

#define F_LEN 192001
#define NFFT  384000
#define NCH   8

__device__ __forceinline__ float2 cmulf(float2 a, float2 b) {
  return make_float2(a.x*b.x - a.y*b.y, a.x*b.y + a.y*b.x);
}
__device__ __forceinline__ float2 caddf2(float2 a, float2 b){ return make_float2(a.x+b.x, a.y+b.y); }
__device__ __forceinline__ float2 csubf2(float2 a, float2 b){ return make_float2(a.x-b.x, a.y-b.y); }

// ---------------- K0: expm(skew(W)) in f64, + md, gamma, AG ----------------
__global__ __launch_bounds__(64) void precompute_kernel(
    const float* __restrict__ W, const float* __restrict__ m,
    double* __restrict__ md_d, float* __restrict__ AG, unsigned int* __restrict__ mxbits)
{
  __shared__ double S[64], P[64], T[64];
  __shared__ double norm_sh;
  const int t = threadIdx.x;
  const int i = t >> 3, j = t & 7;

  double wij = (j > i) ? (double)W[i*8+j] : 0.0;
  double wji = (i > j) ? (double)W[j*8+i] : 0.0;
  S[t] = wij - wji;                       // skew-symmetric S - S^T
  __syncthreads();

  if (t == 0) {
    double best = 0.0;
    for (int r = 0; r < 8; ++r) {
      double rs = 0.0;
      for (int c = 0; c < 8; ++c) rs += fabs(S[r*8+c]);
      best = fmax(best, rs);
    }
    norm_sh = best;
  }
  __syncthreads();

  double nrm = norm_sh;
  int s = 0;
  while (nrm > 0.25 && s < 60) { nrm *= 0.5; ++s; }
  S[t] *= ldexp(1.0, -s);

  P[t] = (i == j) ? 1.0 : 0.0;   // running sum
  T[t] = P[t];                   // current Taylor term
  __syncthreads();

  for (int k = 1; k <= 24; ++k) {
    double acc = 0.0;
    #pragma unroll
    for (int l = 0; l < 8; ++l) acc += T[i*8+l] * S[l*8+j];
    __syncthreads();
    T[t] = acc / (double)k;
    P[t] += T[t];
    __syncthreads();
  }
  for (int q = 0; q < s; ++q) {
    double acc = 0.0;
    #pragma unroll
    for (int l = 0; l < 8; ++l) acc += P[i*8+l] * P[l*8+j];
    __syncthreads();
    P[t] = acc;
    __syncthreads();
  }

  const double M_AVR = 1118.0;
  const double M_STDd = (double)((float)sqrt(419520.0 / 7.0));  // replicate f32-rounded std
  const double LN_GAIN = log(0.9999);

  double md_j  = (double)m[j] * M_STDd + M_AVR;
  double gam_j = exp(md_j * LN_GAIN);
  AG[t] = (float)(P[t] * gam_j);          // A * diag(gamma): column scaling

  if (t < 8) md_d[t] = (double)m[t] * M_STDd + M_AVR;
  if (t == 0) *mxbits = 0u;
}

// ---------------- K1: per-frequency 8x8 complex solve ----------------
__global__ __launch_bounds__(256) void freq_solve_kernel(
    const double* __restrict__ md_d, const float* __restrict__ AG,
    const float* __restrict__ Bp, const float* __restrict__ Cp,
    float* __restrict__ outH, float2* __restrict__ Y, int interleaved)
{
  int f = blockIdx.x * blockDim.x + threadIdx.x;
  if (f >= F_LEN) return;

  const double TWO_PI = 6.283185307179586476925287;
  double fd = (double)f;
  float xc[8], xs[8];
  #pragma unroll
  for (int n = 0; n < 8; ++n) {
    // theta = pi*f/192000 * md = 2*pi * (f*md/384000); reduce in f64, sincos in f32
    double tt = fd * md_d[n] * (1.0 / (double)NFFT);
    tt -= floor(tt);
    float ang = (float)(tt * TWO_PI);
    __sincosf(ang, &xs[n], &xc[n]);
  }

  float2 Mm[8][8];
  float2 yv[8];
  float2 idg[8];
  #pragma unroll
  for (int i = 0; i < 8; ++i) {
    #pragma unroll
    for (int j = 0; j < 8; ++j) {
      float2 v = make_float2(-AG[i*8+j], 0.0f);
      if (i == j) { v.x += xc[i]; v.y = xs[i]; }
      Mm[i][j] = v;
    }
    yv[i] = make_float2(Bp[i], 0.0f);
  }

  // LU without pivoting (M = D - A*Gamma is well-conditioned, ||D^-1 A Gamma|| < 1)
  #pragma unroll
  for (int k = 0; k < 8; ++k) {
    float2 p = Mm[k][k];
    float rd = 1.0f / (p.x*p.x + p.y*p.y);
    float2 inv = make_float2(p.x*rd, -p.y*rd);
    idg[k] = inv;
    #pragma unroll
    for (int i = k+1; i < 8; ++i) {
      float2 fm = cmulf(Mm[i][k], inv);
      #pragma unroll
      for (int j = k+1; j < 8; ++j)
        Mm[i][j] = csubf2(Mm[i][j], cmulf(fm, Mm[k][j]));
      yv[i] = csubf2(yv[i], cmulf(fm, yv[k]));
    }
  }
  // back substitution
  #pragma unroll
  for (int k = 7; k >= 0; --k) {
    float2 acc = yv[k];
    #pragma unroll
    for (int j = k+1; j < 8; ++j)
      acc = csubf2(acc, cmulf(Mm[k][j], yv[j]));
    yv[k] = cmulf(acc, idg[k]);
  }

  float2 hsum = make_float2(0.f, 0.f);
  #pragma unroll
  for (int n = 0; n < 8; ++n) {
    float c = Cp[n];
    float2 H = make_float2(yv[n].x * c, yv[n].y * c);
    yv[n] = H;
    hsum = caddf2(hsum, H);
  }

  if (interleaved) {
    float2* o = (float2*)outH;
    #pragma unroll
    for (int n = 0; n < 8; ++n) o[f*8+n] = yv[n];
  } else {
    #pragma unroll
    for (int n = 0; n < 8; ++n) outH[f*8+n] = yv[n].x;
  }

  // Hermitian-extended spectrum, 1/N folded in
  const float invN = 1.0f / (float)NFFT;
  float2 ysc = make_float2(hsum.x * invN, hsum.y * invN);
  Y[f] = ysc;
  if (f >= 1 && f <= F_LEN - 2) Y[NFFT - f] = make_float2(ysc.x, -ysc.y);
}

// ---------------- inverse-DFT butterflies (sign = +i) ----------------
__device__ __forceinline__ void dft4_inv(float2* v) {
  float2 t0 = caddf2(v[0], v[2]);
  float2 t1 = csubf2(v[0], v[2]);
  float2 t2 = caddf2(v[1], v[3]);
  float2 t3 = csubf2(v[1], v[3]);
  float2 it3 = make_float2(-t3.y, t3.x);
  v[0] = caddf2(t0, t2);
  v[1] = caddf2(t1, it3);
  v[2] = csubf2(t0, t2);
  v[3] = csubf2(t1, it3);
}

template <int R>
__device__ __forceinline__ void dft_inv(float2* v) {
  if constexpr (R == 2) {
    float2 a = v[0], b = v[1];
    v[0] = caddf2(a, b); v[1] = csubf2(a, b);
  } else if constexpr (R == 3) {
    const float S3 = 0.86602540378443864676f;
    float2 t1 = caddf2(v[1], v[2]);
    float2 d  = csubf2(v[1], v[2]);
    float2 u  = make_float2(v[0].x - 0.5f*t1.x, v[0].y - 0.5f*t1.y);
    float2 idd = make_float2(-S3*d.y, S3*d.x);
    v[0] = caddf2(v[0], t1);
    v[1] = caddf2(u, idd);
    v[2] = csubf2(u, idd);
  } else if constexpr (R == 4) {
    dft4_inv(v);
  } else if constexpr (R == 5) {
    const float C1 =  0.30901699437494742410f;
    const float S1 =  0.95105651629515357212f;
    const float C2 = -0.80901699437494742410f;
    const float S2 =  0.58778525229247312917f;
    float2 t1 = caddf2(v[1], v[4]);
    float2 t2 = caddf2(v[2], v[3]);
    float2 t3 = csubf2(v[1], v[4]);
    float2 t4 = csubf2(v[2], v[3]);
    float2 x0 = v[0];
    float2 a1 = make_float2(x0.x + C1*t1.x + C2*t2.x, x0.y + C1*t1.y + C2*t2.y);
    float2 b1 = make_float2(S1*t3.x + S2*t4.x,        S1*t3.y + S2*t4.y);
    float2 a2 = make_float2(x0.x + C2*t1.x + C1*t2.x, x0.y + C2*t1.y + C1*t2.y);
    float2 b2 = make_float2(S2*t3.x - S1*t4.x,        S2*t3.y - S1*t4.y);
    float2 ib1 = make_float2(-b1.y, b1.x);
    float2 ib2 = make_float2(-b2.y, b2.x);
    v[0] = make_float2(x0.x + t1.x + t2.x, x0.y + t1.y + t2.y);
    v[1] = caddf2(a1, ib1);
    v[4] = csubf2(a1, ib1);
    v[2] = caddf2(a2, ib2);
    v[3] = csubf2(a2, ib2);
  } else if constexpr (R == 8) {
    const float HF = 0.70710678118654752440f;
    float2 e[4] = {v[0], v[2], v[4], v[6]};
    float2 o[4] = {v[1], v[3], v[5], v[7]};
    dft4_inv(e); dft4_inv(o);
    o[1] = cmulf(o[1], make_float2(HF, HF));
    o[2] = make_float2(-o[2].y, o[2].x);
    o[3] = cmulf(o[3], make_float2(-HF, HF));
    #pragma unroll
    for (int k = 0; k < 4; ++k) {
      v[k]   = caddf2(e[k], o[k]);
      v[k+4] = csubf2(e[k], o[k]);
    }
  }
}

// ---------------- Stockham pass (inverse, no normalization) ----------------
template <int R>
__global__ __launch_bounds__(256) void fft_pass(
    const float2* __restrict__ in, float2* __restrict__ out, int Ns)
{
  constexpr int NT = NFFT / R;
  int j = blockIdx.x * blockDim.x + threadIdx.x;
  if (j >= NT) return;
  int jm = j % Ns;
  int jd = j / Ns;

  float2 v[R];
  double tb = (double)jm / (double)(Ns * R);   // twiddle angle unit in turns
  #pragma unroll
  for (int r = 0; r < R; ++r) {
    float2 x = in[j + r * NT];
    if (r > 0) {
      float ang = (float)(6.283185307179586476925287 * (tb * (double)r));
      float sn, cs; __sincosf(ang, &sn, &cs);
      x = cmulf(x, make_float2(cs, sn));       // +i convention (inverse)
    }
    v[r] = x;
  }
  dft_inv<R>(v);
  int base = jd * (Ns * R) + jm;
  #pragma unroll
  for (int r = 0; r < R; ++r) out[base + r * Ns] = v[r];
}

// ---------------- max |Re| reduction ----------------
__global__ __launch_bounds__(256) void absmax_kernel(
    const float2* __restrict__ Yf, unsigned int* __restrict__ mx)
{
  __shared__ unsigned int sm[256];
  int tid = threadIdx.x;
  float m = 0.f;
  for (int t = blockIdx.x * blockDim.x + tid; t < NFFT; t += gridDim.x * blockDim.x)
    m = fmaxf(m, fabsf(Yf[t].x));
  sm[tid] = __float_as_uint(m);
  __syncthreads();
  #pragma unroll
  for (int s = 128; s > 0; s >>= 1) {
    if (tid < s) sm[tid] = max(sm[tid], sm[tid + s]);
    __syncthreads();
  }
  if (tid == 0) atomicMax(mx, sm[0]);
}

// ---------------- normalize real part into h ----------------
__global__ __launch_bounds__(256) void norm_kernel(
    const float2* __restrict__ Yf, const unsigned int* __restrict__ mx,
    float* __restrict__ hout)
{
  int t = blockIdx.x * blockDim.x + threadIdx.x;
  if (t >= NFFT) return;
  float mxv = __uint_as_float(*mx);
  hout[t] = Yf[t].x / mxv;
}

extern "C" void kernel_launch(void* const* d_in, const int* in_sizes, int n_in,
                              void* d_out, int out_size, void* d_ws, size_t ws_size,
                              hipStream_t stream)
{
  const float* Bp = (const float*)d_in[1];
  const float* Cp = (const float*)d_in[2];
  const float* Wp = (const float*)d_in[3];
  const float* mp = (const float*)d_in[4];

  char* ws = (char*)d_ws;
  double* md_d = (double*)ws;                 // 8 doubles @ 0
  float*  AG   = (float*)(ws + 64);           // 64 floats @ 64
  unsigned int* mx = (unsigned int*)(ws + 384);
  float2* buf0 = (float2*)(ws + 512);         // NFFT complex
  float2* buf1 = buf0 + NFFT;                 // NFFT complex

  float* outf = (float*)d_out;
  const int hoff = out_size - NFFT;
  const int interleaved = (hoff >= 2 * F_LEN * NCH) ? 1 : 0;

  precompute_kernel<<<1, 64, 0, stream>>>(Wp, mp, md_d, AG, mx);
  freq_solve_kernel<<<(F_LEN + 255) / 256, 256, 0, stream>>>(
      md_d, AG, Bp, Cp, outf, buf0, interleaved);

  // Stockham inverse FFT: 384000 = 8*8*4*4*3*5*5*5
  float2* a = buf0; float2* b = buf1;
  int Ns = 1;
  fft_pass<8><<<(NFFT/8 + 255)/256, 256, 0, stream>>>(a, b, Ns); Ns *= 8; { float2* t_ = a; a = b; b = t_; }
  fft_pass<8><<<(NFFT/8 + 255)/256, 256, 0, stream>>>(a, b, Ns); Ns *= 8; { float2* t_ = a; a = b; b = t_; }
  fft_pass<4><<<(NFFT/4 + 255)/256, 256, 0, stream>>>(a, b, Ns); Ns *= 4; { float2* t_ = a; a = b; b = t_; }
  fft_pass<4><<<(NFFT/4 + 255)/256, 256, 0, stream>>>(a, b, Ns); Ns *= 4; { float2* t_ = a; a = b; b = t_; }
  fft_pass<3><<<(NFFT/3 + 255)/256, 256, 0, stream>>>(a, b, Ns); Ns *= 3; { float2* t_ = a; a = b; b = t_; }
  fft_pass<5><<<(NFFT/5 + 255)/256, 256, 0, stream>>>(a, b, Ns); Ns *= 5; { float2* t_ = a; a = b; b = t_; }
  fft_pass<5><<<(NFFT/5 + 255)/256, 256, 0, stream>>>(a, b, Ns); Ns *= 5; { float2* t_ = a; a = b; b = t_; }
  fft_pass<5><<<(NFFT/5 + 255)/256, 256, 0, stream>>>(a, b, Ns); Ns *= 5; { float2* t_ = a; a = b; b = t_; }
  // after 8 passes result is back in buf0 (== a)

  absmax_kernel<<<512, 256, 0, stream>>>(a, mx);
  norm_kernel<<<(NFFT + 255)/256, 256, 0, stream>>>(a, mx, outf + hoff);
}

// Round 2
// 43.512 us; speedup vs baseline: 1.4352x; 1.4352x over previous
//
#include <hip/hip_runtime.h>
#include <math.h>

#define F_LEN 192001
#define NFFT  384000
#define MHALF 192000
#define NCH   8

__device__ __forceinline__ float2 cmulf(float2 a, float2 b) {
  return make_float2(a.x*b.x - a.y*b.y, a.x*b.y + a.y*b.x);
}
__device__ __forceinline__ float2 caddf2(float2 a, float2 b){ return make_float2(a.x+b.x, a.y+b.y); }
__device__ __forceinline__ float2 csubf2(float2 a, float2 b){ return make_float2(a.x-b.x, a.y-b.y); }

// ---------------- K0: expm(skew(W)) in f64, + md, gamma, AG ----------------
__global__ __launch_bounds__(64) void precompute_kernel(
    const float* __restrict__ W, const float* __restrict__ m,
    double* __restrict__ md_d, float* __restrict__ AG, unsigned int* __restrict__ mxbits)
{
  __shared__ double S[64], P[64], T[64];
  __shared__ double norm_sh;
  const int t = threadIdx.x;
  const int i = t >> 3, j = t & 7;

  double wij = (j > i) ? (double)W[i*8+j] : 0.0;
  double wji = (i > j) ? (double)W[j*8+i] : 0.0;
  S[t] = wij - wji;                       // skew-symmetric S - S^T
  __syncthreads();

  if (t == 0) {
    double best = 0.0;
    for (int r = 0; r < 8; ++r) {
      double rs = 0.0;
      for (int c = 0; c < 8; ++c) rs += fabs(S[r*8+c]);
      best = fmax(best, rs);
    }
    norm_sh = best;
  }
  __syncthreads();

  double nrm = norm_sh;
  int s = 0;
  while (nrm > 0.25 && s < 60) { nrm *= 0.5; ++s; }
  S[t] *= ldexp(1.0, -s);

  P[t] = (i == j) ? 1.0 : 0.0;   // running sum
  T[t] = P[t];                   // current Taylor term
  __syncthreads();

  for (int k = 1; k <= 24; ++k) {
    double acc = 0.0;
    #pragma unroll
    for (int l = 0; l < 8; ++l) acc += T[i*8+l] * S[l*8+j];
    __syncthreads();
    T[t] = acc / (double)k;
    P[t] += T[t];
    __syncthreads();
  }
  for (int q = 0; q < s; ++q) {
    double acc = 0.0;
    #pragma unroll
    for (int l = 0; l < 8; ++l) acc += P[i*8+l] * P[l*8+j];
    __syncthreads();
    P[t] = acc;
    __syncthreads();
  }

  const double M_AVR = 1118.0;
  const double M_STDd = (double)((float)sqrt(419520.0 / 7.0));  // replicate f32-rounded std
  const double LN_GAIN = log(0.9999);

  double md_j  = (double)m[j] * M_STDd + M_AVR;
  double gam_j = exp(md_j * LN_GAIN);
  AG[t] = (float)(P[t] * gam_j);          // A * diag(gamma): column scaling

  if (t < 8) md_d[t] = (double)m[t] * M_STDd + M_AVR;
  if (t == 0) *mxbits = 0u;
}

// ---------------- K1: per-frequency 8x8 complex solve ----------------
__global__ __launch_bounds__(256) void freq_solve_kernel(
    const double* __restrict__ md_d, const float* __restrict__ AG,
    const float* __restrict__ Bp, const float* __restrict__ Cp,
    float* __restrict__ outH, float2* __restrict__ Y, int interleaved)
{
  int f = blockIdx.x * blockDim.x + threadIdx.x;
  if (f >= F_LEN) return;

  const double TWO_PI = 6.283185307179586476925287;
  double fd = (double)f;
  float xc[8], xs[8];
  #pragma unroll
  for (int n = 0; n < 8; ++n) {
    // theta = pi*f/192000 * md = 2*pi * (f*md/384000); reduce in f64, sincos in f32
    double tt = fd * md_d[n] * (1.0 / (double)NFFT);
    tt -= floor(tt);
    float ang = (float)(tt * TWO_PI);
    __sincosf(ang, &xs[n], &xc[n]);
  }

  float2 Mm[8][8];
  float2 yv[8];
  float2 idg[8];
  #pragma unroll
  for (int i = 0; i < 8; ++i) {
    #pragma unroll
    for (int j = 0; j < 8; ++j) {
      float2 v = make_float2(-AG[i*8+j], 0.0f);
      if (i == j) { v.x += xc[i]; v.y = xs[i]; }
      Mm[i][j] = v;
    }
    yv[i] = make_float2(Bp[i], 0.0f);
  }

  // LU without pivoting (M = D - A*Gamma is well-conditioned, ||D^-1 A Gamma|| < 1)
  #pragma unroll
  for (int k = 0; k < 8; ++k) {
    float2 p = Mm[k][k];
    float rd = 1.0f / (p.x*p.x + p.y*p.y);
    float2 inv = make_float2(p.x*rd, -p.y*rd);
    idg[k] = inv;
    #pragma unroll
    for (int i = k+1; i < 8; ++i) {
      float2 fm = cmulf(Mm[i][k], inv);
      #pragma unroll
      for (int j = k+1; j < 8; ++j)
        Mm[i][j] = csubf2(Mm[i][j], cmulf(fm, Mm[k][j]));
      yv[i] = csubf2(yv[i], cmulf(fm, yv[k]));
    }
  }
  // back substitution
  #pragma unroll
  for (int k = 7; k >= 0; --k) {
    float2 acc = yv[k];
    #pragma unroll
    for (int j = k+1; j < 8; ++j)
      acc = csubf2(acc, cmulf(Mm[k][j], yv[j]));
    yv[k] = cmulf(acc, idg[k]);
  }

  float2 hsum = make_float2(0.f, 0.f);
  #pragma unroll
  for (int n = 0; n < 8; ++n) {
    float c = Cp[n];
    float2 H = make_float2(yv[n].x * c, yv[n].y * c);
    yv[n] = H;
    hsum = caddf2(hsum, H);
  }

  if (interleaved) {
    float2* o = (float2*)outH;
    #pragma unroll
    for (int n = 0; n < 8; ++n) o[f*8+n] = yv[n];
  } else {
    #pragma unroll
    for (int n = 0; n < 8; ++n) outH[f*8+n] = yv[n].x;
  }

  // one-sided spectrum, unscaled (normalization cancels the 1/N)
  Y[f] = hsum;
}

// ---------------- inverse-DFT butterflies (sign = +i) ----------------
__device__ __forceinline__ void dft4_inv(float2* v) {
  float2 t0 = caddf2(v[0], v[2]);
  float2 t1 = csubf2(v[0], v[2]);
  float2 t2 = caddf2(v[1], v[3]);
  float2 t3 = csubf2(v[1], v[3]);
  float2 it3 = make_float2(-t3.y, t3.x);
  v[0] = caddf2(t0, t2);
  v[1] = caddf2(t1, it3);
  v[2] = csubf2(t0, t2);
  v[3] = csubf2(t1, it3);
}

__device__ __forceinline__ void dft3_inv(float2* v) {
  const float S3 = 0.86602540378443864676f;
  float2 t1 = caddf2(v[1], v[2]);
  float2 d  = csubf2(v[1], v[2]);
  float2 u  = make_float2(v[0].x - 0.5f*t1.x, v[0].y - 0.5f*t1.y);
  float2 idd = make_float2(-S3*d.y, S3*d.x);
  v[0] = caddf2(v[0], t1);
  v[1] = caddf2(u, idd);
  v[2] = csubf2(u, idd);
}

__device__ __forceinline__ void dft5_inv(float2* v) {
  const float C1 =  0.30901699437494742410f;
  const float S1 =  0.95105651629515357212f;
  const float C2 = -0.80901699437494742410f;
  const float S2 =  0.58778525229247312917f;
  float2 t1 = caddf2(v[1], v[4]);
  float2 t2 = caddf2(v[2], v[3]);
  float2 t3 = csubf2(v[1], v[4]);
  float2 t4 = csubf2(v[2], v[3]);
  float2 x0 = v[0];
  float2 a1 = make_float2(x0.x + C1*t1.x + C2*t2.x, x0.y + C1*t1.y + C2*t2.y);
  float2 b1 = make_float2(S1*t3.x + S2*t4.x,        S1*t3.y + S2*t4.y);
  float2 a2 = make_float2(x0.x + C2*t1.x + C1*t2.x, x0.y + C2*t1.y + C1*t2.y);
  float2 b2 = make_float2(S2*t3.x - S1*t4.x,        S2*t3.y - S1*t4.y);
  float2 ib1 = make_float2(-b1.y, b1.x);
  float2 ib2 = make_float2(-b2.y, b2.x);
  v[0] = make_float2(x0.x + t1.x + t2.x, x0.y + t1.y + t2.y);
  v[1] = caddf2(a1, ib1);
  v[4] = csubf2(a1, ib1);
  v[2] = caddf2(a2, ib2);
  v[3] = csubf2(a2, ib2);
}

// twiddle table for radix-25 (cos/sin of 2*pi*m/25), +i convention
__device__ __constant__ float TW25[25][2] = {
  { 1.0f, 0.0f },
  { 0.9685831611286311f,  0.2486898871648548f },
  { 0.8763066800438636f,  0.4817536741017153f },
  { 0.7289686274214116f,  0.6845471059286887f },
  { 0.5358267949789967f,  0.8443279255020151f },
  { 0.3090169943749474f,  0.9510565162951535f },
  { 0.0627905195293134f,  0.9980267284282716f },
  {-0.1873813145857246f,  0.9822872507286887f },
  {-0.4257792915650727f,  0.9048270524660196f },
  {-0.6374239897486896f,  0.7705132427757893f },
  {-0.8090169943749474f,  0.5877852522924731f },
  {-0.9297764858882515f,  0.3681245526846780f },
  {-0.9921147013144779f,  0.1253332335643043f },
  {-0.9921147013144779f, -0.1253332335643043f },
  {-0.9297764858882515f, -0.3681245526846780f },
  {-0.8090169943749474f, -0.5877852522924731f },
  {-0.6374239897486899f, -0.7705132427757891f },
  {-0.4257792915650727f, -0.9048270524660196f },
  {-0.1873813145857246f, -0.9822872507286887f },
  { 0.0627905195293134f, -0.9980267284282716f },
  { 0.3090169943749474f, -0.9510565162951535f },
  { 0.5358267949789967f, -0.8443279255020151f },
  { 0.7289686274214116f, -0.6845471059286887f },
  { 0.8763066800438636f, -0.4817536741017153f },
  { 0.9685831611286311f, -0.2486898871648548f },
};

template <int R>
__device__ __forceinline__ void dft_inv(float2* v) {
  if constexpr (R == 3) {
    dft3_inv(v);
  } else if constexpr (R == 4) {
    dft4_inv(v);
  } else if constexpr (R == 5) {
    dft5_inv(v);
  } else if constexpr (R == 8) {
    const float HF = 0.70710678118654752440f;
    float2 e[4] = {v[0], v[2], v[4], v[6]};
    float2 o[4] = {v[1], v[3], v[5], v[7]};
    dft4_inv(e); dft4_inv(o);
    o[1] = cmulf(o[1], make_float2(HF, HF));
    o[2] = make_float2(-o[2].y, o[2].x);
    o[3] = cmulf(o[3], make_float2(-HF, HF));
    #pragma unroll
    for (int k = 0; k < 4; ++k) {
      v[k]   = caddf2(e[k], o[k]);
      v[k+4] = csubf2(e[k], o[k]);
    }
  } else if constexpr (R == 15) {
    // Good-Thomas PFA 3x5: no twiddles. n=(5n1+3n2)%15, k=(10k1+6k2)%15
    float2 a[5][3];
    #pragma unroll
    for (int n2 = 0; n2 < 5; ++n2) {
      #pragma unroll
      for (int n1 = 0; n1 < 3; ++n1)
        a[n2][n1] = v[(5*n1 + 3*n2) % 15];
      dft3_inv(a[n2]);            // over n1 -> k1
    }
    #pragma unroll
    for (int k1 = 0; k1 < 3; ++k1) {
      float2 b[5];
      #pragma unroll
      for (int n2 = 0; n2 < 5; ++n2) b[n2] = a[n2][k1];
      dft5_inv(b);                // over n2 -> k2
      #pragma unroll
      for (int k2 = 0; k2 < 5; ++k2) v[(10*k1 + 6*k2) % 15] = b[k2];
    }
  } else if constexpr (R == 25) {
    // Cooley-Tukey 5x5: n=5n1+n2, k=k1+5k2, twiddle w25^(n2*k1)
    float2 a[5][5];               // [k1][n2]
    #pragma unroll
    for (int n2 = 0; n2 < 5; ++n2) {
      float2 b[5];
      #pragma unroll
      for (int n1 = 0; n1 < 5; ++n1) b[n1] = v[5*n1 + n2];
      dft5_inv(b);                // over n1 -> k1
      #pragma unroll
      for (int k1 = 0; k1 < 5; ++k1) a[k1][n2] = b[k1];
    }
    #pragma unroll
    for (int k1 = 1; k1 < 5; ++k1) {
      #pragma unroll
      for (int n2 = 1; n2 < 5; ++n2) {
        const int mm = (n2 * k1) % 25;
        a[k1][n2] = cmulf(a[k1][n2], make_float2(TW25[mm][0], TW25[mm][1]));
      }
    }
    #pragma unroll
    for (int k1 = 0; k1 < 5; ++k1) {
      dft5_inv(a[k1]);            // over n2 -> k2
      #pragma unroll
      for (int k2 = 0; k2 < 5; ++k2) v[k1 + 5*k2] = a[k1][k2];
    }
  }
}

// ---------------- pass 1: irfft pack (one-sided Y -> Z) + radix-8, Ns=1 ----------------
__global__ __launch_bounds__(256) void fft_first8(
    const float2* __restrict__ Y, float2* __restrict__ out)
{
  constexpr int NT = MHALF / 8;
  int j = blockIdx.x * blockDim.x + threadIdx.x;
  if (j >= NT) return;

  float2 v[8];
  #pragma unroll
  for (int r = 0; r < 8; ++r) {
    int t = j + r * NT;
    float2 Ya = Y[t];
    float2 Ym = Y[MHALF - t];
    if (t == 0) { Ya.y = 0.f; Ym.y = 0.f; }  // pocketfft ignores imag of DC/Nyquist
    // E = Ya + conj(Ym); Oc = Ya - conj(Ym); O = e^{+i*2pi*t/NFFT} * Oc; Z = E + i*O
    float2 E  = make_float2(Ya.x + Ym.x, Ya.y - Ym.y);
    float2 Oc = make_float2(Ya.x - Ym.x, Ya.y + Ym.y);
    double tt = (double)t * (1.0 / (double)NFFT);
    float ang = (float)(6.283185307179586476925287 * tt);
    float sn, cs; __sincosf(ang, &sn, &cs);
    float2 O = make_float2(cs*Oc.x - sn*Oc.y, cs*Oc.y + sn*Oc.x);
    v[r] = make_float2(E.x - O.y, E.y + O.x);
  }
  dft_inv<8>(v);
  int base = j * 8;                          // Ns=1: contiguous 64B store per thread
  #pragma unroll
  for (int r = 0; r < 8; ++r) out[base + r] = v[r];
}

// ---------------- Stockham pass (inverse), optional fused absmax ----------------
template <int R, bool DOMAX>
__global__ __launch_bounds__(256) void fft_pass(
    const float2* __restrict__ in, float2* __restrict__ out, int Ns,
    unsigned int* __restrict__ mx)
{
  constexpr int NT = MHALF / R;
  int j = blockIdx.x * blockDim.x + threadIdx.x;
  if (j >= NT) return;
  int jm = j % Ns;
  int jd = j / Ns;

  float2 v[R];
  double tb = (double)jm / (double)(Ns * R);   // twiddle angle in turns
  #pragma unroll
  for (int r = 0; r < R; ++r) {
    float2 x = in[j + r * NT];
    if (r > 0) {
      float ang = (float)(6.283185307179586476925287 * (tb * (double)r));
      float sn, cs; __sincosf(ang, &sn, &cs);
      x = cmulf(x, make_float2(cs, sn));       // +i convention (inverse)
    }
    v[r] = x;
  }
  dft_inv<R>(v);
  int base = jd * (Ns * R) + jm;
  #pragma unroll
  for (int r = 0; r < R; ++r) out[base + r * Ns] = v[r];

  if constexpr (DOMAX) {
    float m = 0.f;
    #pragma unroll
    for (int r = 0; r < R; ++r)
      m = fmaxf(m, fmaxf(fabsf(v[r].x), fabsf(v[r].y)));
    #pragma unroll
    for (int off = 32; off > 0; off >>= 1)
      m = fmaxf(m, __shfl_xor(m, off));
    if ((threadIdx.x & 63) == 0) atomicMax(mx, __float_as_uint(m));
  }
}

// ---------------- normalize + unpack: h[2n]=Re z[n], h[2n+1]=Im z[n] ----------------
__global__ __launch_bounds__(256) void norm_kernel(
    const float2* __restrict__ z, const unsigned int* __restrict__ mx,
    float2* __restrict__ hout)
{
  int n = blockIdx.x * blockDim.x + threadIdx.x;
  if (n >= MHALF) return;
  float mxv = __uint_as_float(*mx);
  float2 zz = z[n];
  hout[n] = make_float2(zz.x / mxv, zz.y / mxv);
}

extern "C" void kernel_launch(void* const* d_in, const int* in_sizes, int n_in,
                              void* d_out, int out_size, void* d_ws, size_t ws_size,
                              hipStream_t stream)
{
  const float* Bp = (const float*)d_in[1];
  const float* Cp = (const float*)d_in[2];
  const float* Wp = (const float*)d_in[3];
  const float* mp = (const float*)d_in[4];

  char* ws = (char*)d_ws;
  double* md_d = (double*)ws;                    // 8 doubles @ 0
  float*  AG   = (float*)(ws + 64);              // 64 floats @ 64
  unsigned int* mx = (unsigned int*)(ws + 384);
  float2* bufY = (float2*)(ws + 512);            // F_LEN complex (one-sided spectrum)
  float2* bufA = (float2*)(ws + 512 + 1536128);  // MHALF complex
  float2* bufB = bufA + MHALF;                   // MHALF complex

  float* outf = (float*)d_out;
  const int hoff = out_size - NFFT;
  const int interleaved = (hoff >= 2 * F_LEN * NCH) ? 1 : 0;

  precompute_kernel<<<1, 64, 0, stream>>>(Wp, mp, md_d, AG, mx);
  freq_solve_kernel<<<(F_LEN + 255) / 256, 256, 0, stream>>>(
      md_d, AG, Bp, Cp, outf, bufY, interleaved);

  // inverse complex FFT of size 192000 = 8*8*8*15*25 (Stockham, 5 passes)
  fft_first8<<<(MHALF/8 + 255)/256, 256, 0, stream>>>(bufY, bufA);                       // Ns 1->8
  fft_pass<8,  false><<<(MHALF/8  + 255)/256, 256, 0, stream>>>(bufA, bufB, 8,    mx);   // ->64
  fft_pass<8,  false><<<(MHALF/8  + 255)/256, 256, 0, stream>>>(bufB, bufA, 64,   mx);   // ->512
  fft_pass<15, false><<<(MHALF/15 + 255)/256, 256, 0, stream>>>(bufA, bufB, 512,  mx);   // ->7680
  fft_pass<25, true ><<<(MHALF/25 + 255)/256, 256, 0, stream>>>(bufB, bufA, 7680, mx);   // ->192000

  norm_kernel<<<(MHALF + 255)/256, 256, 0, stream>>>(bufA, mx, (float2*)(outf + hoff));
}

// Round 3
// 37.479 us; speedup vs baseline: 1.6662x; 1.1610x over previous
//
#include <hip/hip_runtime.h>
#include <math.h>

#define F_LEN 192001
#define NFFT  384000
#define MHALF 192000
#define NCH   8

__device__ __forceinline__ float2 cmulf(float2 a, float2 b) {
  return make_float2(a.x*b.x - a.y*b.y, a.x*b.y + a.y*b.x);
}
__device__ __forceinline__ float2 caddf2(float2 a, float2 b){ return make_float2(a.x+b.x, a.y+b.y); }
__device__ __forceinline__ float2 csubf2(float2 a, float2 b){ return make_float2(a.x-b.x, a.y-b.y); }

// ---------------- K0: expm(skew(W)) in f64, + md, gamma, AG ----------------
__global__ __launch_bounds__(64) void precompute_kernel(
    const float* __restrict__ W, const float* __restrict__ m,
    double* __restrict__ md_d, float* __restrict__ AG, unsigned int* __restrict__ mxbits)
{
  __shared__ double S[64], P[64], T[64];
  __shared__ double norm_sh;
  const int t = threadIdx.x;
  const int i = t >> 3, j = t & 7;

  double wij = (j > i) ? (double)W[i*8+j] : 0.0;
  double wji = (i > j) ? (double)W[j*8+i] : 0.0;
  S[t] = wij - wji;                       // skew-symmetric S - S^T
  __syncthreads();

  if (t == 0) {
    double best = 0.0;
    for (int r = 0; r < 8; ++r) {
      double rs = 0.0;
      for (int c = 0; c < 8; ++c) rs += fabs(S[r*8+c]);
      best = fmax(best, rs);
    }
    norm_sh = best;
  }
  __syncthreads();

  double nrm = norm_sh;
  int s = 0;
  while (nrm > 0.5 && s < 60) { nrm *= 0.5; ++s; }
  S[t] *= ldexp(1.0, -s);

  P[t] = (i == j) ? 1.0 : 0.0;   // running sum
  T[t] = P[t];                   // current Taylor term
  __syncthreads();

  for (int k = 1; k <= 13; ++k) {
    double acc = 0.0;
    #pragma unroll
    for (int l = 0; l < 8; ++l) acc += T[i*8+l] * S[l*8+j];
    __syncthreads();
    T[t] = acc / (double)k;
    P[t] += T[t];
    __syncthreads();
  }
  for (int q = 0; q < s; ++q) {
    double acc = 0.0;
    #pragma unroll
    for (int l = 0; l < 8; ++l) acc += P[i*8+l] * P[l*8+j];
    __syncthreads();
    P[t] = acc;
    __syncthreads();
  }

  const double M_AVR = 1118.0;
  const double M_STDd = (double)((float)sqrt(419520.0 / 7.0));  // replicate f32-rounded std
  const double LN_GAIN = log(0.9999);

  double md_j  = (double)m[j] * M_STDd + M_AVR;
  double gam_j = exp(md_j * LN_GAIN);
  AG[t] = (float)(P[t] * gam_j);          // A * diag(gamma): column scaling

  if (t < 8) md_d[t] = (double)m[t] * M_STDd + M_AVR;
  if (t == 0) *mxbits = 0u;
}

// ---------------- K1: per-frequency 8x8 complex solve ----------------
__global__ __launch_bounds__(256) void freq_solve_kernel(
    const double* __restrict__ md_d, const float* __restrict__ AG,
    const float* __restrict__ Bp, const float* __restrict__ Cp,
    float* __restrict__ outH, float2* __restrict__ Y, int interleaved)
{
  int f = blockIdx.x * blockDim.x + threadIdx.x;
  if (f >= F_LEN) return;

  const double TWO_PI = 6.283185307179586476925287;
  double fd = (double)f;
  float xc[8], xs[8];
  #pragma unroll
  for (int n = 0; n < 8; ++n) {
    double tt = fd * md_d[n] * (1.0 / (double)NFFT);
    tt -= floor(tt);
    float ang = (float)(tt * TWO_PI);
    __sincosf(ang, &xs[n], &xc[n]);
  }

  float2 Mm[8][8];
  float2 yv[8];
  float2 idg[8];
  #pragma unroll
  for (int i = 0; i < 8; ++i) {
    #pragma unroll
    for (int j = 0; j < 8; ++j) {
      float2 v = make_float2(-AG[i*8+j], 0.0f);
      if (i == j) { v.x += xc[i]; v.y = xs[i]; }
      Mm[i][j] = v;
    }
    yv[i] = make_float2(Bp[i], 0.0f);
  }

  // LU without pivoting (M = D - A*Gamma is well-conditioned)
  #pragma unroll
  for (int k = 0; k < 8; ++k) {
    float2 p = Mm[k][k];
    float rd = 1.0f / (p.x*p.x + p.y*p.y);
    float2 inv = make_float2(p.x*rd, -p.y*rd);
    idg[k] = inv;
    #pragma unroll
    for (int i = k+1; i < 8; ++i) {
      float2 fm = cmulf(Mm[i][k], inv);
      #pragma unroll
      for (int j = k+1; j < 8; ++j)
        Mm[i][j] = csubf2(Mm[i][j], cmulf(fm, Mm[k][j]));
      yv[i] = csubf2(yv[i], cmulf(fm, yv[k]));
    }
  }
  #pragma unroll
  for (int k = 7; k >= 0; --k) {
    float2 acc = yv[k];
    #pragma unroll
    for (int j = k+1; j < 8; ++j)
      acc = csubf2(acc, cmulf(Mm[k][j], yv[j]));
    yv[k] = cmulf(acc, idg[k]);
  }

  float2 hsum = make_float2(0.f, 0.f);
  #pragma unroll
  for (int n = 0; n < 8; ++n) {
    float c = Cp[n];
    float2 H = make_float2(yv[n].x * c, yv[n].y * c);
    yv[n] = H;
    hsum = caddf2(hsum, H);
  }

  if (interleaved) {
    float2* o = (float2*)outH;
    #pragma unroll
    for (int n = 0; n < 8; ++n) o[f*8+n] = yv[n];
  } else {
    #pragma unroll
    for (int n = 0; n < 8; ++n) outH[f*8+n] = yv[n].x;
  }

  Y[f] = hsum;   // one-sided spectrum, unscaled (normalization cancels 1/N)
}

// ---------------- inverse-DFT butterflies (sign = +i) ----------------
__device__ __forceinline__ void dft4_inv(float2* v) {
  float2 t0 = caddf2(v[0], v[2]);
  float2 t1 = csubf2(v[0], v[2]);
  float2 t2 = caddf2(v[1], v[3]);
  float2 t3 = csubf2(v[1], v[3]);
  float2 it3 = make_float2(-t3.y, t3.x);
  v[0] = caddf2(t0, t2);
  v[1] = caddf2(t1, it3);
  v[2] = csubf2(t0, t2);
  v[3] = csubf2(t1, it3);
}

__device__ __forceinline__ void dft3_inv(float2* v) {
  const float S3 = 0.86602540378443864676f;
  float2 t1 = caddf2(v[1], v[2]);
  float2 d  = csubf2(v[1], v[2]);
  float2 u  = make_float2(v[0].x - 0.5f*t1.x, v[0].y - 0.5f*t1.y);
  float2 idd = make_float2(-S3*d.y, S3*d.x);
  v[0] = caddf2(v[0], t1);
  v[1] = caddf2(u, idd);
  v[2] = csubf2(u, idd);
}

__device__ __forceinline__ void dft5_inv(float2* v) {
  const float C1 =  0.30901699437494742410f;
  const float S1 =  0.95105651629515357212f;
  const float C2 = -0.80901699437494742410f;
  const float S2 =  0.58778525229247312917f;
  float2 t1 = caddf2(v[1], v[4]);
  float2 t2 = caddf2(v[2], v[3]);
  float2 t3 = csubf2(v[1], v[4]);
  float2 t4 = csubf2(v[2], v[3]);
  float2 x0 = v[0];
  float2 a1 = make_float2(x0.x + C1*t1.x + C2*t2.x, x0.y + C1*t1.y + C2*t2.y);
  float2 b1 = make_float2(S1*t3.x + S2*t4.x,        S1*t3.y + S2*t4.y);
  float2 a2 = make_float2(x0.x + C2*t1.x + C1*t2.x, x0.y + C2*t1.y + C1*t2.y);
  float2 b2 = make_float2(S2*t3.x - S1*t4.x,        S2*t3.y - S1*t4.y);
  float2 ib1 = make_float2(-b1.y, b1.x);
  float2 ib2 = make_float2(-b2.y, b2.x);
  v[0] = make_float2(x0.x + t1.x + t2.x, x0.y + t1.y + t2.y);
  v[1] = caddf2(a1, ib1);
  v[4] = csubf2(a1, ib1);
  v[2] = caddf2(a2, ib2);
  v[3] = csubf2(a2, ib2);
}

__device__ __forceinline__ void dft8_inv(float2* v) {
  const float HF = 0.70710678118654752440f;
  float2 e[4] = {v[0], v[2], v[4], v[6]};
  float2 o[4] = {v[1], v[3], v[5], v[7]};
  dft4_inv(e); dft4_inv(o);
  o[1] = cmulf(o[1], make_float2(HF, HF));
  o[2] = make_float2(-o[2].y, o[2].x);
  o[3] = cmulf(o[3], make_float2(-HF, HF));
  #pragma unroll
  for (int k = 0; k < 4; ++k) {
    v[k]   = caddf2(e[k], o[k]);
    v[k+4] = csubf2(e[k], o[k]);
  }
}

__device__ __forceinline__ void dft15_inv(float2* v) {
  // Good-Thomas PFA 3x5: no twiddles. n=(5n1+3n2)%15, k=(10k1+6k2)%15
  float2 a[5][3];
  #pragma unroll
  for (int n2 = 0; n2 < 5; ++n2) {
    #pragma unroll
    for (int n1 = 0; n1 < 3; ++n1)
      a[n2][n1] = v[(5*n1 + 3*n2) % 15];
    dft3_inv(a[n2]);
  }
  #pragma unroll
  for (int k1 = 0; k1 < 3; ++k1) {
    float2 b[5];
    #pragma unroll
    for (int n2 = 0; n2 < 5; ++n2) b[n2] = a[n2][k1];
    dft5_inv(b);
    #pragma unroll
    for (int k2 = 0; k2 < 5; ++k2) v[(10*k1 + 6*k2) % 15] = b[k2];
  }
}

__device__ __constant__ float TW25[25][2] = {
  { 1.0f, 0.0f },
  { 0.9685831611286311f,  0.2486898871648548f },
  { 0.8763066800438636f,  0.4817536741017153f },
  { 0.7289686274214116f,  0.6845471059286887f },
  { 0.5358267949789967f,  0.8443279255020151f },
  { 0.3090169943749474f,  0.9510565162951535f },
  { 0.0627905195293134f,  0.9980267284282716f },
  {-0.1873813145857246f,  0.9822872507286887f },
  {-0.4257792915650727f,  0.9048270524660196f },
  {-0.6374239897486896f,  0.7705132427757893f },
  {-0.8090169943749474f,  0.5877852522924731f },
  {-0.9297764858882515f,  0.3681245526846780f },
  {-0.9921147013144779f,  0.1253332335643043f },
  {-0.9921147013144779f, -0.1253332335643043f },
  {-0.9297764858882515f, -0.3681245526846780f },
  {-0.8090169943749474f, -0.5877852522924731f },
  {-0.6374239897486899f, -0.7705132427757891f },
  {-0.4257792915650727f, -0.9048270524660196f },
  {-0.1873813145857246f, -0.9822872507286887f },
  { 0.0627905195293134f, -0.9980267284282716f },
  { 0.3090169943749474f, -0.9510565162951535f },
  { 0.5358267949789967f, -0.8443279255020151f },
  { 0.7289686274214116f, -0.6845471059286887f },
  { 0.8763066800438636f, -0.4817536741017153f },
  { 0.9685831611286311f, -0.2486898871648548f },
};

__device__ __forceinline__ void dft25_inv(float2* v) {
  // Cooley-Tukey 5x5: n=5n1+n2, k=k1+5k2, twiddle w25^(n2*k1)
  float2 a[5][5];               // [k1][n2]
  #pragma unroll
  for (int n2 = 0; n2 < 5; ++n2) {
    float2 b[5];
    #pragma unroll
    for (int n1 = 0; n1 < 5; ++n1) b[n1] = v[5*n1 + n2];
    dft5_inv(b);
    #pragma unroll
    for (int k1 = 0; k1 < 5; ++k1) a[k1][n2] = b[k1];
  }
  #pragma unroll
  for (int k1 = 1; k1 < 5; ++k1) {
    #pragma unroll
    for (int n2 = 1; n2 < 5; ++n2) {
      const int mm = (n2 * k1) % 25;
      a[k1][n2] = cmulf(a[k1][n2], make_float2(TW25[mm][0], TW25[mm][1]));
    }
  }
  #pragma unroll
  for (int k1 = 0; k1 < 5; ++k1) {
    dft5_inv(a[k1]);
    #pragma unroll
    for (int k2 = 0; k2 < 5; ++k2) v[k1 + 5*k2] = a[k1][k2];
  }
}

// ---------------- fftA: irfft pack + full 512-pt FFT per wave (LDS) ----------------
// out[d*512 + k] = DFT512( Z[d + 375*t], t )[k],  d in [0,375)
// Z[n] packed from one-sided Y. 3 waves/block, each wave owns a padded LDS slice.
__global__ __launch_bounds__(192) void fftA_kernel(
    const float2* __restrict__ Y, float2* __restrict__ out)
{
  __shared__ float2 lds[3][576];            // 512 + pad (idx + idx/8)
  const int wave = threadIdx.x >> 6;
  const int l = threadIdx.x & 63;
  const int d = blockIdx.x * 3 + wave;      // grid 125*3 == 375 exactly
  float2* A = lds[wave];
  const double TWO_PI = 6.283185307179586476925287;

  float2 v[8];
  // load + pack + stage1 (Ns=1, no twiddle)
  #pragma unroll
  for (int r = 0; r < 8; ++r) {
    int t = l + 64*r;
    int n = d + 375*t;                      // [0, 192000)
    float2 Ya = Y[n];
    float2 Ym = Y[MHALF - n];
    if (n == 0) { Ya.y = 0.f; Ym.y = 0.f; } // c2r ignores imag of DC/Nyquist
    float2 E  = make_float2(Ya.x + Ym.x, Ya.y - Ym.y);
    float2 Oc = make_float2(Ya.x - Ym.x, Ya.y + Ym.y);
    double tt = (double)n * (1.0 / (double)NFFT);
    float ang = (float)(TWO_PI * tt);
    float sn, cs; __sincosf(ang, &sn, &cs);
    float2 O = make_float2(cs*Oc.x - sn*Oc.y, cs*Oc.y + sn*Oc.x);
    v[r] = make_float2(E.x - O.y, E.y + O.x);
  }
  dft8_inv(v);
  #pragma unroll
  for (int r = 0; r < 8; ++r) { int idx = 8*l + r; A[idx + (idx>>3)] = v[r]; }
  __syncthreads();

  // stage2: Ns=8
  {
    int jm = l & 7, jd = l >> 3;
    #pragma unroll
    for (int r = 0; r < 8; ++r) { int idx = l + 64*r; v[r] = A[idx + (idx>>3)]; }
    double tb = (double)jm * (1.0/64.0);
    #pragma unroll
    for (int r = 1; r < 8; ++r) {
      float ang = (float)(TWO_PI * tb * (double)r);
      float sn, cs; __sincosf(ang, &sn, &cs);
      v[r] = cmulf(v[r], make_float2(cs, sn));
    }
    dft8_inv(v);
    __syncthreads();                        // all reads done before overwrite
    #pragma unroll
    for (int r = 0; r < 8; ++r) { int idx = jd*64 + jm + 8*r; A[idx + (idx>>3)] = v[r]; }
  }
  __syncthreads();

  // stage3: Ns=64 -> registers -> coalesced global store
  {
    #pragma unroll
    for (int r = 0; r < 8; ++r) { int idx = l + 64*r; v[r] = A[idx + (idx>>3)]; }
    double tb = (double)l * (1.0/512.0);
    #pragma unroll
    for (int r = 1; r < 8; ++r) {
      float ang = (float)(TWO_PI * tb * (double)r);
      float sn, cs; __sincosf(ang, &sn, &cs);
      v[r] = cmulf(v[r], make_float2(cs, sn));
    }
    dft8_inv(v);
    #pragma unroll
    for (int r = 0; r < 8; ++r) out[d*512 + l + 64*r] = v[r];
  }
}

// ---------------- fftB: per-jm 375-pt transform (15 then 25) + absmax ----------------
// in[d*512 + jm] = DFT512 results; out[jm + 512*u] = final X.  jm-tile = 8 per block.
__global__ __launch_bounds__(256) void fftB_kernel(
    const float2* __restrict__ Ain, float2* __restrict__ out, unsigned int* __restrict__ mx)
{
  __shared__ float2 lds[375*9];             // [d][jm_l] padded row 9
  const int tid = threadIdx.x;
  const int J0 = blockIdx.x * 8;
  const double TWO_PI = 6.283185307179586476925287;

  // coalesced load: 3000 = 375*8 elements
  #pragma unroll
  for (int k = 0; k < 12; ++k) {
    int i = tid + 256*k;
    if (i < 3000) {
      int d = i >> 3, jl = i & 7;
      lds[d*9 + jl] = Ain[d*512 + J0 + jl];
    }
  }
  __syncthreads();

  // phase 1: 200 dft15 items (jm_l, jd)
  {
    bool act = tid < 200;
    int jl = tid & 7, jd = tid >> 3;        // jd in [0,25)
    float2 p[15];
    if (act) {
      #pragma unroll
      for (int r = 0; r < 15; ++r) p[r] = lds[(jd + 25*r)*9 + jl];
    }
    __syncthreads();                        // all reads complete
    if (act) {
      int jm = J0 + jl;
      double tb = (double)jm * (1.0/7680.0);
      #pragma unroll
      for (int r = 1; r < 15; ++r) {
        float ang = (float)(TWO_PI * tb * (double)r);
        float sn, cs; __sincosf(ang, &sn, &cs);
        p[r] = cmulf(p[r], make_float2(cs, sn));
      }
      dft15_inv(p);
      #pragma unroll
      for (int r = 0; r < 15; ++r) lds[(15*jd + r)*9 + jl] = p[r];
    }
  }
  __syncthreads();

  // phase 2: 120 dft25 items (jm_l, s) -> global + absmax
  float mloc = 0.f;
  {
    bool act = tid < 120;
    int jl = tid & 7, s = tid >> 3;         // s in [0,15)
    float2 q[25];
    if (act) {
      #pragma unroll
      for (int r = 0; r < 25; ++r) q[r] = lds[(s + 15*r)*9 + jl];
      int jm = J0 + jl;
      int j = jm + 512*s;
      double tb = (double)j * (1.0/(double)MHALF);
      #pragma unroll
      for (int r = 1; r < 25; ++r) {
        float ang = (float)(TWO_PI * tb * (double)r);
        float sn, cs; __sincosf(ang, &sn, &cs);
        q[r] = cmulf(q[r], make_float2(cs, sn));
      }
      dft25_inv(q);
      #pragma unroll
      for (int r = 0; r < 25; ++r) {
        out[jm + 512*(s + 15*r)] = q[r];
        mloc = fmaxf(mloc, fmaxf(fabsf(q[r].x), fabsf(q[r].y)));
      }
    }
  }
  #pragma unroll
  for (int off = 32; off > 0; off >>= 1)
    mloc = fmaxf(mloc, __shfl_xor(mloc, off));
  if ((tid & 63) == 0) atomicMax(mx, __float_as_uint(mloc));
}

// ---------------- normalize + unpack (float4 = 2 complex per thread) ----------------
__global__ __launch_bounds__(256) void norm_kernel(
    const float4* __restrict__ z, const unsigned int* __restrict__ mx,
    float4* __restrict__ hout)
{
  int n = blockIdx.x * blockDim.x + threadIdx.x;
  if (n >= MHALF/2) return;
  float r = 1.0f / __uint_as_float(*mx);
  float4 zz = z[n];
  hout[n] = make_float4(zz.x*r, zz.y*r, zz.z*r, zz.w*r);
}

extern "C" void kernel_launch(void* const* d_in, const int* in_sizes, int n_in,
                              void* d_out, int out_size, void* d_ws, size_t ws_size,
                              hipStream_t stream)
{
  const float* Bp = (const float*)d_in[1];
  const float* Cp = (const float*)d_in[2];
  const float* Wp = (const float*)d_in[3];
  const float* mp = (const float*)d_in[4];

  char* ws = (char*)d_ws;
  double* md_d = (double*)ws;                    // 8 doubles @ 0
  float*  AG   = (float*)(ws + 64);              // 64 floats @ 64
  unsigned int* mx = (unsigned int*)(ws + 384);
  float2* bufY = (float2*)(ws + 512);            // F_LEN complex (one-sided spectrum)
  float2* bufA = (float2*)(ws + 512 + 1536128);  // MHALF complex
  float2* bufB = bufA + MHALF;                   // MHALF complex

  float* outf = (float*)d_out;
  const int hoff = out_size - NFFT;
  const int interleaved = (hoff >= 2 * F_LEN * NCH) ? 1 : 0;

  precompute_kernel<<<1, 64, 0, stream>>>(Wp, mp, md_d, AG, mx);
  freq_solve_kernel<<<(F_LEN + 255) / 256, 256, 0, stream>>>(
      md_d, AG, Bp, Cp, outf, bufY, interleaved);

  // inverse complex FFT of 192000 = 512 x 375, two LDS kernels
  fftA_kernel<<<125, 192, 0, stream>>>(bufY, bufA);
  fftB_kernel<<<64, 256, 0, stream>>>(bufA, bufB, mx);

  norm_kernel<<<(MHALF/2 + 255)/256, 256, 0, stream>>>(
      (const float4*)bufB, mx, (float4*)(outf + hoff));
}